// Round 9
// baseline (416.933 us; speedup 1.0000x reference)
//
#include <hip/hip_runtime.h>
#include <math.h>

#define NN 50000
#define EE 600000
#define DD 128
#define GG 64
#define NCLS 10
#define PCHUNK 128
#define SCHUNK 1024
#define NCHUNK ((NN + SCHUNK - 1) / SCHUNK)

typedef __attribute__((ext_vector_type(8))) __bf16 bf16x8;
typedef __attribute__((ext_vector_type(8))) unsigned short u16x8;
typedef __attribute__((ext_vector_type(4))) float f32x4;

__device__ __forceinline__ unsigned short f2bf(float f) {
    unsigned int u = __float_as_uint(f);
    u += 0x7fff + ((u >> 16) & 1);     // round-to-nearest-even
    return (unsigned short)(u >> 16);
}

__device__ __forceinline__ float bf2f(unsigned short h) {
    return __uint_as_float(((unsigned int)h) << 16);
}

// ---------------- CSR build (split chain: beats grid.sync on MI355X, R7) ----

__global__ void hist_kernel(const int* __restrict__ dst, int* __restrict__ cnt, int e) {
    int i = blockIdx.x * blockDim.x + threadIdx.x;
    if (i < e) atomicAdd(&cnt[dst[i]], 1);
}

__global__ __launch_bounds__(1024) void scan1_kernel(const int* __restrict__ cnt,
                                                     int* __restrict__ lexcl,
                                                     int* __restrict__ csum, int n) {
    __shared__ int wsum[16];
    int tid = threadIdx.x;
    int lane = tid & 63, wid = tid >> 6;
    int i = blockIdx.x * SCHUNK + tid;
    int v = (i < n) ? cnt[i] : 0;
    int x = v;
    #pragma unroll
    for (int off = 1; off < 64; off <<= 1) {
        int y = __shfl_up(x, off);
        if (lane >= off) x += y;
    }
    if (lane == 63) wsum[wid] = x;
    __syncthreads();
    if (wid == 0) {
        int ws = (lane < 16) ? wsum[lane] : 0;
        int xs = ws;
        #pragma unroll
        for (int off = 1; off < 16; off <<= 1) {
            int y = __shfl_up(xs, off);
            if (lane >= off) xs += y;
        }
        if (lane < 16) wsum[lane] = xs - ws;
    }
    __syncthreads();
    if (i < n) lexcl[i] = wsum[wid] + x - v;
    if (tid == 1023) csum[blockIdx.x] = wsum[15] + x;
}

// scan of chunk totals folded in (each block redundantly scans the 49 totals)
__global__ __launch_bounds__(1024) void scan3_kernel(const int* __restrict__ lexcl,
                                                     const int* __restrict__ csum,
                                                     int* __restrict__ indptr,
                                                     int* __restrict__ cursor,
                                                     int n, int total) {
    __shared__ int base_s;
    int t = threadIdx.x;
    if (t < 64) {
        int v = (t < NCHUNK) ? csum[t] : 0;
        int x = v;
        #pragma unroll
        for (int off = 1; off < 64; off <<= 1) {
            int y = __shfl_up(x, off);
            if (t >= off) x += y;
        }
        if (t == (int)blockIdx.x) base_s = x - v;   // exclusive prefix for this chunk
    }
    __syncthreads();
    int i = blockIdx.x * SCHUNK + t;
    if (i < n) {
        int val = lexcl[i] + base_s;
        indptr[i] = val;
        cursor[i] = val;
    }
    if (i == 0) indptr[n] = total;
}

__global__ void fill_kernel(const int* __restrict__ src, const int* __restrict__ dst,
                            int* __restrict__ cursor, int* __restrict__ esrc, int e) {
    int i = blockIdx.x * blockDim.x + threadIdx.x;
    if (i < e) {
        int pos = atomicAdd(&cursor[dst[i]], 1);
        esrc[pos] = src[i];
    }
}

// ---------------- weight pre-transpose + bf16 convert ----------------

__global__ void wt_kernel(const float* __restrict__ wq, const float* __restrict__ wk,
                          const float* __restrict__ wv, const float* __restrict__ ws,
                          unsigned short* __restrict__ wt) {
    int idx = blockIdx.x * 256 + threadIdx.x;
    int k = idx & 127;
    int n = (idx >> 7) & 127;
    int lm = idx >> 14;
    int l = lm >> 2, m = lm & 3;
    const float* w = (m == 0) ? wq : (m == 1) ? wk : (m == 2) ? wv : ws;
    wt[idx] = f2bf(w[l * 16384 + k * 128 + n]);
}

// ---------------- bf16 MFMA QKVS GEMM: 32-row strip, all 4 mats, bf16 out ----
// 1563 blocks (~6/CU) so memory latency hides behind other blocks (R8: 782
// blocks @3/CU sat idle). All outputs bf16: halves write traffic.

template <bool IN_BF16>
__global__ __launch_bounds__(256) void gemm_mfma(
    const void* __restrict__ xin,
    const unsigned short* __restrict__ wt,      // [4][128][128] bf16, n-major
    const float* __restrict__ bq, const float* __restrict__ bk,
    const float* __restrict__ bv, const float* __restrict__ bs,
    unsigned short* __restrict__ qb, unsigned short* __restrict__ kb,
    unsigned short* __restrict__ vb, unsigned short* __restrict__ sb) {
    __shared__ __align__(16) unsigned short As[32 * 136];

    int t = threadIdx.x;
    int row0 = blockIdx.x * 32;

    int kg = t & 15, rb = t >> 4;
    #pragma unroll
    for (int i = 0; i < 2; ++i) {
        int row = rb + i * 16;                  // 0..31
        int grow = row0 + row;
        u16x8 a8 = {0, 0, 0, 0, 0, 0, 0, 0};
        if (grow < NN) {
            if (IN_BF16) {
                a8 = *(const u16x8*)((const unsigned short*)xin + (size_t)grow * DD + kg * 8);
            } else {
                const float* p = (const float*)xin + (size_t)grow * DD + kg * 8;
                float4 f0 = *(const float4*)p;
                float4 f1 = *(const float4*)(p + 4);
                a8[0] = f2bf(f0.x); a8[1] = f2bf(f0.y); a8[2] = f2bf(f0.z); a8[3] = f2bf(f0.w);
                a8[4] = f2bf(f1.x); a8[5] = f2bf(f1.y); a8[6] = f2bf(f1.z); a8[7] = f2bf(f1.w);
            }
        }
        *(u16x8*)&As[row * 136 + kg * 8] = a8;
    }
    __syncthreads();

    int lane = t & 63;
    int wave = t >> 6;
    int wm = wave >> 1, wn = wave & 1;          // 16-row half / 64-col half
    int lr = lane & 15, quad = lane >> 4;

    #pragma unroll
    for (int mat = 0; mat < 4; ++mat) {
        const unsigned short* wm_ = wt + mat * 16384;
        const float* bias = (mat == 0) ? bq : (mat == 1) ? bk : (mat == 2) ? bv : bs;
        unsigned short* outp = (mat == 0) ? qb : (mat == 1) ? kb : (mat == 2) ? vb : sb;

        bf16x8 bfr[4][4];
        #pragma unroll
        for (int ks = 0; ks < 4; ++ks)
            #pragma unroll
            for (int tn = 0; tn < 4; ++tn)
                bfr[ks][tn] = *(const bf16x8*)(wm_ + (wn * 64 + tn * 16 + lr) * 128
                                                    + ks * 32 + quad * 8);

        f32x4 acc[4];
        #pragma unroll
        for (int b = 0; b < 4; ++b) acc[b] = (f32x4){0.f, 0.f, 0.f, 0.f};

        #pragma unroll
        for (int ks = 0; ks < 4; ++ks) {
            bf16x8 af = *(const bf16x8*)&As[(wm * 16 + lr) * 136 + ks * 32 + quad * 8];
            #pragma unroll
            for (int tn = 0; tn < 4; ++tn)
                acc[tn] = __builtin_amdgcn_mfma_f32_16x16x32_bf16(
                    af, bfr[ks][tn], acc[tn], 0, 0, 0);
        }

        // C/D layout: col = lane&15, row = quad*4 + reg
        #pragma unroll
        for (int tn = 0; tn < 4; ++tn) {
            int col = wn * 64 + tn * 16 + lr;
            float bv_ = bias[col];
            int nb = row0 + wm * 16 + quad * 4;
            #pragma unroll
            for (int r = 0; r < 4; ++r) {
                int node = nb + r;
                if (node < NN)
                    outp[(size_t)node * DD + col] = f2bf(acc[tn][r] + bv_);
            }
        }
    }
}

// ---------------- attention: 4 edges/wave via 16-lane subgroups ----------------
// all q/k/v/s bf16 in, h bf16 out.

__global__ __launch_bounds__(256) void attn_kernel(
    const unsigned short* __restrict__ qb, const unsigned short* __restrict__ kb,
    const unsigned short* __restrict__ vb, const unsigned short* __restrict__ sb,
    const int* __restrict__ indptr, const int* __restrict__ esrc,
    unsigned short* __restrict__ hout, int n) {
    int node = (int)((blockIdx.x * blockDim.x + threadIdx.x) >> 6);
    int lane = threadIdx.x & 63;
    if (node >= n) return;
    int g = lane >> 4, j = lane & 15;

    u16x8 q8 = *(const u16x8*)(qb + (size_t)node * DD + j * 8);
    float qf[8];
    #pragma unroll
    for (int c = 0; c < 8; ++c) qf[c] = bf2f(q8[c]);

    int beg = indptr[node], end = indptr[node + 1];

    float m = -3.0e38f, den = 0.f;
    float acc[8];
    #pragma unroll
    for (int c = 0; c < 8; ++c) acc[c] = 0.f;

    for (int e = beg + g; e < end; e += 4) {
        int sidx = esrc[e];
        u16x8 k8 = *(const u16x8*)(kb + (size_t)sidx * DD + j * 8);
        u16x8 v8 = *(const u16x8*)(vb + (size_t)sidx * DD + j * 8);
        float p;
        p  = qf[0] * bf2f(k8[0]);
        p  = fmaf(qf[1], bf2f(k8[1]), p);
        p  = fmaf(qf[2], bf2f(k8[2]), p);
        p  = fmaf(qf[3], bf2f(k8[3]), p);
        p  = fmaf(qf[4], bf2f(k8[4]), p);
        p  = fmaf(qf[5], bf2f(k8[5]), p);
        p  = fmaf(qf[6], bf2f(k8[6]), p);
        p  = fmaf(qf[7], bf2f(k8[7]), p);
        p += __shfl_xor(p, 8);
        p += __shfl_xor(p, 4);
        p += __shfl_xor(p, 2);
        p += __shfl_xor(p, 1);
        float score = p * 0.088388347648318447f;   // 1/sqrt(128)
        float mn = fmaxf(m, score);
        float scale = __expf(m - mn);
        float pe = __expf(score - mn);
        den = den * scale + pe;
        #pragma unroll
        for (int c = 0; c < 8; ++c)
            acc[c] = fmaf(acc[c], scale, pe * bf2f(v8[c]));
        m = mn;
    }

    float mo = __shfl_xor(m, 16);
    float m2 = fmaxf(m, mo);
    mo = __shfl_xor(m2, 32);
    float mf = fmaxf(m2, mo);
    float sc = __expf(m - mf);
    den *= sc;
    den += __shfl_xor(den, 16);
    den += __shfl_xor(den, 32);
    #pragma unroll
    for (int c = 0; c < 8; ++c) {
        float a = acc[c] * sc;
        a += __shfl_xor(a, 16);
        a += __shfl_xor(a, 32);
        acc[c] = a;
    }
    float inv = den > 0.f ? 1.0f / den : 0.f;
    if (g == 0) {
        u16x8 s8 = *(const u16x8*)(sb + (size_t)node * DD + j * 8);
        u16x8 o8;
        #pragma unroll
        for (int c = 0; c < 8; ++c)
            o8[c] = f2bf(fmaxf(fmaf(acc[c], inv, bf2f(s8[c])), 0.f));
        *(u16x8*)(hout + (size_t)node * DD + j * 8) = o8;
    }
}

// ---------------- global mean pool (h bf16): segmented running sum ----------

__global__ __launch_bounds__(128) void pool_kernel(const unsigned short* __restrict__ h,
                                                   const int* __restrict__ batch,
                                                   float* __restrict__ gsum,
                                                   float* __restrict__ gcnt, int n) {
    __shared__ int bsh[PCHUNK];
    int t = threadIdx.x;
    int node0 = blockIdx.x * PCHUNK;
    int nnodes = min(PCHUNK, n - node0);
    if (t < nnodes) bsh[t] = batch[node0 + t];
    __syncthreads();

    int cur = bsh[0];
    float acc = 0.f;
    int cnt = 0;
    for (int j = 0; j < nnodes; ++j) {
        int g = bsh[j];
        float val = bf2f(h[(size_t)(node0 + j) * DD + t]);
        if (g != cur) {
            atomicAdd(&gsum[cur * DD + t], acc);
            if (t == 0) atomicAdd(&gcnt[cur], (float)cnt);
            acc = 0.f; cnt = 0; cur = g;
        }
        acc += val; ++cnt;
    }
    if (cnt > 0) {
        atomicAdd(&gsum[cur * DD + t], acc);
        if (t == 0) atomicAdd(&gcnt[cur], (float)cnt);
    }
}

// ---------------- FC + log_softmax ----------------

__global__ __launch_bounds__(64) void head_kernel(
    const float* __restrict__ gsum, const float* __restrict__ gcnt,
    const float* __restrict__ wfc, const float* __restrict__ bfc,
    float* __restrict__ out) {
    int g = blockIdx.x;
    int lane = threadIdx.x;
    float cnt = fmaxf(gcnt[g], 1.0f);
    float inv = 1.0f / cnt;
    float p0 = gsum[g * DD + lane] * inv;
    float p1 = gsum[g * DD + lane + 64] * inv;
    __shared__ float logits[NCLS];
    for (int c = 0; c < NCLS; ++c) {
        float partial = p0 * wfc[lane * NCLS + c] + p1 * wfc[(lane + 64) * NCLS + c];
        partial += __shfl_xor(partial, 32);
        partial += __shfl_xor(partial, 16);
        partial += __shfl_xor(partial, 8);
        partial += __shfl_xor(partial, 4);
        partial += __shfl_xor(partial, 2);
        partial += __shfl_xor(partial, 1);
        if (lane == 0) logits[c] = partial + bfc[c];
    }
    __syncthreads();
    if (lane == 0) {
        float mx = logits[0];
        for (int c = 1; c < NCLS; ++c) mx = fmaxf(mx, logits[c]);
        float sum = 0.f;
        for (int c = 0; c < NCLS; ++c) sum += expf(logits[c] - mx);
        float lse = mx + logf(sum);
        for (int c = 0; c < NCLS; ++c) out[g * NCLS + c] = logits[c] - lse;
    }
}

// ---------------- launch ----------------

extern "C" void kernel_launch(void* const* d_in, const int* in_sizes, int n_in,
                              void* d_out, int out_size, void* d_ws, size_t ws_size,
                              hipStream_t stream) {
    const float* x     = (const float*)d_in[0];
    const int*   ei    = (const int*)d_in[1];
    const int*   batch = (const int*)d_in[2];
    const float* Wq = (const float*)d_in[3];
    const float* bq = (const float*)d_in[4];
    const float* Wk = (const float*)d_in[5];
    const float* bk = (const float*)d_in[6];
    const float* Wv = (const float*)d_in[7];
    const float* bv = (const float*)d_in[8];
    const float* Ws = (const float*)d_in[9];
    const float* bs = (const float*)d_in[10];
    const float* Wfc = (const float*)d_in[11];
    const float* bfc = (const float*)d_in[12];
    float* out = (float*)d_out;

    const size_t ND = (size_t)NN * DD;
    unsigned short* hbuf = (unsigned short*)d_ws;   // all bf16 now
    unsigned short* qb = hbuf + ND;
    unsigned short* sb = qb + ND;
    unsigned short* kb = sb + ND;
    unsigned short* vb = kb + ND;
    unsigned short* wt = vb + ND;                   // [2][4][128][128] bf16
    int* cnt    = (int*)(wt + 2 * 4 * 16384);
    int* indptr = cnt + NN;
    int* cursor = indptr + NN + 1;
    int* esrc   = cursor + NN;
    int* lexcl  = esrc + EE;
    int* csum   = lexcl + NN;
    float* gsum = (float*)(csum + NCHUNK);
    float* gcnt = gsum + GG * DD;

    const int* src = ei;
    const int* dst = ei + EE;

    hipMemsetAsync(cnt, 0, NN * sizeof(int), stream);
    hipMemsetAsync(gsum, 0, (GG * DD + GG) * sizeof(float), stream);

    hist_kernel<<<(EE + 255) / 256, 256, 0, stream>>>(dst, cnt, EE);
    scan1_kernel<<<NCHUNK, 1024, 0, stream>>>(cnt, lexcl, csum, NN);
    scan3_kernel<<<NCHUNK, 1024, 0, stream>>>(lexcl, csum, indptr, cursor, NN, EE);
    fill_kernel<<<(EE + 255) / 256, 256, 0, stream>>>(src, dst, cursor, esrc, EE);
    wt_kernel<<<512, 256, 0, stream>>>(Wq, Wk, Wv, Ws, wt);

    for (int l = 0; l < 2; ++l) {
        size_t bo = (size_t)l * DD;
        const unsigned short* wtl = wt + (size_t)l * 4 * 16384;
        if (l == 0)
            gemm_mfma<false><<<(NN + 31) / 32, 256, 0, stream>>>(
                (const void*)x, wtl, bq + bo, bk + bo, bv + bo, bs + bo,
                qb, kb, vb, sb);
        else
            gemm_mfma<true><<<(NN + 31) / 32, 256, 0, stream>>>(
                (const void*)hbuf, wtl, bq + bo, bk + bo, bv + bo, bs + bo,
                qb, kb, vb, sb);
        attn_kernel<<<(NN + 3) / 4, 256, 0, stream>>>(
            qb, kb, vb, sb, indptr, esrc, hbuf, NN);
    }

    pool_kernel<<<(NN + PCHUNK - 1) / PCHUNK, 128, 0, stream>>>(hbuf, batch, gsum, gcnt, NN);
    head_kernel<<<GG, 64, 0, stream>>>(gsum, gcnt, Wfc, bfc, out);
}

// Round 10
// 340.895 us; speedup vs baseline: 1.2231x; 1.2231x over previous
//
#include <hip/hip_runtime.h>
#include <math.h>

#define NN 50000
#define EE 600000
#define DD 128
#define GG 64
#define NCLS 10
#define PCHUNK 128
#define SCHUNK 1024
#define NCHUNK ((NN + SCHUNK - 1) / SCHUNK)
#define NTILE (NN / 16)            // 3125 row-tiles, exact

typedef __attribute__((ext_vector_type(8))) __bf16 bf16x8;
typedef __attribute__((ext_vector_type(8))) unsigned short u16x8;
typedef __attribute__((ext_vector_type(4))) float f32x4;

__device__ __forceinline__ unsigned short f2bf(float f) {
    unsigned int u = __float_as_uint(f);
    u += 0x7fff + ((u >> 16) & 1);     // round-to-nearest-even
    return (unsigned short)(u >> 16);
}

__device__ __forceinline__ float bf2f(unsigned short h) {
    return __uint_as_float(((unsigned int)h) << 16);
}

// ---------------- CSR build (split chain; beats grid.sync on MI355X, R7) ----

__global__ void hist_kernel(const int* __restrict__ dst, int* __restrict__ cnt, int e) {
    int i = blockIdx.x * blockDim.x + threadIdx.x;
    if (i < e) atomicAdd(&cnt[dst[i]], 1);
}

__global__ __launch_bounds__(1024) void scan1_kernel(const int* __restrict__ cnt,
                                                     int* __restrict__ lexcl,
                                                     int* __restrict__ csum, int n) {
    __shared__ int wsum[16];
    int tid = threadIdx.x;
    int lane = tid & 63, wid = tid >> 6;
    int i = blockIdx.x * SCHUNK + tid;
    int v = (i < n) ? cnt[i] : 0;
    int x = v;
    #pragma unroll
    for (int off = 1; off < 64; off <<= 1) {
        int y = __shfl_up(x, off);
        if (lane >= off) x += y;
    }
    if (lane == 63) wsum[wid] = x;
    __syncthreads();
    if (wid == 0) {
        int ws = (lane < 16) ? wsum[lane] : 0;
        int xs = ws;
        #pragma unroll
        for (int off = 1; off < 16; off <<= 1) {
            int y = __shfl_up(xs, off);
            if (lane >= off) xs += y;
        }
        if (lane < 16) wsum[lane] = xs - ws;
    }
    __syncthreads();
    if (i < n) lexcl[i] = wsum[wid] + x - v;
    if (tid == 1023) csum[blockIdx.x] = wsum[15] + x;
}

__global__ __launch_bounds__(1024) void scan3_kernel(const int* __restrict__ lexcl,
                                                     const int* __restrict__ csum,
                                                     int* __restrict__ indptr,
                                                     int* __restrict__ cursor,
                                                     int n, int total) {
    __shared__ int base_s;
    int t = threadIdx.x;
    if (t < 64) {
        int v = (t < NCHUNK) ? csum[t] : 0;
        int x = v;
        #pragma unroll
        for (int off = 1; off < 64; off <<= 1) {
            int y = __shfl_up(x, off);
            if (t >= off) x += y;
        }
        if (t == (int)blockIdx.x) base_s = x - v;
    }
    __syncthreads();
    int i = blockIdx.x * SCHUNK + t;
    if (i < n) {
        int val = lexcl[i] + base_s;
        indptr[i] = val;
        cursor[i] = val;
    }
    if (i == 0) indptr[n] = total;
}

__global__ void fill_kernel(const int* __restrict__ src, const int* __restrict__ dst,
                            int* __restrict__ cursor, int* __restrict__ esrc, int e) {
    int i = blockIdx.x * blockDim.x + threadIdx.x;
    if (i < e) {
        int pos = atomicAdd(&cursor[dst[i]], 1);
        esrc[pos] = src[i];
    }
}

// ---------------- weight pre-transpose + bf16 convert ----------------

__global__ void wt_kernel(const float* __restrict__ wq, const float* __restrict__ wk,
                          const float* __restrict__ wv, const float* __restrict__ ws,
                          unsigned short* __restrict__ wt) {
    int idx = blockIdx.x * 256 + threadIdx.x;
    int k = idx & 127;
    int n = (idx >> 7) & 127;
    int lm = idx >> 14;
    int l = lm >> 2, m = lm & 3;
    const float* w = (m == 0) ? wq : (m == 1) ? wk : (m == 2) ? wv : ws;
    wt[idx] = f2bf(w[l * 16384 + k * 128 + n]);
}

// ---------------- x fp32 -> bf16 (once; layer-1 input h is already bf16) ----

__global__ void x2bf_kernel(const float* __restrict__ x, unsigned short* __restrict__ xb) {
    int i = blockIdx.x * 256 + threadIdx.x;     // one u16x8 per thread
    const float* p = x + (size_t)i * 8;
    float4 f0 = *(const float4*)p;
    float4 f1 = *(const float4*)(p + 4);
    u16x8 a8;
    a8[0] = f2bf(f0.x); a8[1] = f2bf(f0.y); a8[2] = f2bf(f0.z); a8[3] = f2bf(f0.w);
    a8[4] = f2bf(f1.x); a8[5] = f2bf(f1.y); a8[6] = f2bf(f1.z); a8[7] = f2bf(f1.w);
    *(u16x8*)(xb + (size_t)i * 8) = a8;
}

// ---------------- persistent-wave LDS-free bf16 MFMA GEMM ------------------
// 2048 waves; wave's (mat, col-half) fixed -> 16 B frags register-resident,
// loaded ONCE. A frags read straight from global (row-major bf16 == fragment
// order). No LDS, no barriers -> compiler pipelines tile t+1 loads under
// tile t MFMAs. Kills the ~27ns/block B-reload chain that bound R8/R9.

__global__ __launch_bounds__(256, 4) void gemm_mfma(
    const unsigned short* __restrict__ xa,      // [NN][128] bf16
    const unsigned short* __restrict__ wt,      // [4][128][128] bf16, n-major
    const float* __restrict__ bq, const float* __restrict__ bk,
    const float* __restrict__ bv, const float* __restrict__ bs,
    unsigned short* __restrict__ qb, unsigned short* __restrict__ kb,
    unsigned short* __restrict__ vb, unsigned short* __restrict__ sb) {
    int gw = blockIdx.x * 4 + (threadIdx.x >> 6);   // 0..2047
    int lane = threadIdx.x & 63;
    int mat = (gw >> 1) & 3;
    int ch = gw & 1;                                 // column half
    int wseq = gw >> 3;                              // 0..255
    int lr = lane & 15, quad = lane >> 4;

    const unsigned short* wm_ = wt + mat * 16384;
    const float* bias = (mat == 0) ? bq : (mat == 1) ? bk : (mat == 2) ? bv : bs;
    unsigned short* outp = (mat == 0) ? qb : (mat == 1) ? kb : (mat == 2) ? vb : sb;

    // B fragments: register-resident for the whole kernel
    bf16x8 bfr[4][4];                                // [ks][tn]
    #pragma unroll
    for (int ks = 0; ks < 4; ++ks)
        #pragma unroll
        for (int tn = 0; tn < 4; ++tn)
            bfr[ks][tn] = *(const bf16x8*)(wm_ + (ch * 64 + tn * 16 + lr) * 128
                                               + ks * 32 + quad * 8);
    float bcol[4];
    #pragma unroll
    for (int tn = 0; tn < 4; ++tn) bcol[tn] = bias[ch * 64 + tn * 16 + lr];

    for (int tile = wseq; tile < NTILE; tile += 256) {
        int row0 = tile * 16;
        bf16x8 af[4];
        #pragma unroll
        for (int ks = 0; ks < 4; ++ks)
            af[ks] = *(const bf16x8*)(xa + (size_t)(row0 + lr) * DD + ks * 32 + quad * 8);

        f32x4 acc[4];
        #pragma unroll
        for (int tn = 0; tn < 4; ++tn) acc[tn] = (f32x4){0.f, 0.f, 0.f, 0.f};
        #pragma unroll
        for (int ks = 0; ks < 4; ++ks)
            #pragma unroll
            for (int tn = 0; tn < 4; ++tn)
                acc[tn] = __builtin_amdgcn_mfma_f32_16x16x32_bf16(
                    af[ks], bfr[ks][tn], acc[tn], 0, 0, 0);

        // C/D layout: col = lane&15, row = quad*4 + reg
        #pragma unroll
        for (int tn = 0; tn < 4; ++tn) {
            int col = ch * 64 + tn * 16 + lr;
            int nb = row0 + quad * 4;
            #pragma unroll
            for (int r = 0; r < 4; ++r)
                outp[(size_t)(nb + r) * DD + col] = f2bf(acc[tn][r] + bcol[tn]);
        }
    }
}

// ---------------- attention: 4 edges/wave via 16-lane subgroups ----------------

__global__ __launch_bounds__(256) void attn_kernel(
    const unsigned short* __restrict__ qb, const unsigned short* __restrict__ kb,
    const unsigned short* __restrict__ vb, const unsigned short* __restrict__ sb,
    const int* __restrict__ indptr, const int* __restrict__ esrc,
    unsigned short* __restrict__ hout, int n) {
    int node = (int)((blockIdx.x * blockDim.x + threadIdx.x) >> 6);
    int lane = threadIdx.x & 63;
    if (node >= n) return;
    int g = lane >> 4, j = lane & 15;

    u16x8 q8 = *(const u16x8*)(qb + (size_t)node * DD + j * 8);
    float qf[8];
    #pragma unroll
    for (int c = 0; c < 8; ++c) qf[c] = bf2f(q8[c]);

    int beg = indptr[node], end = indptr[node + 1];

    float m = -3.0e38f, den = 0.f;
    float acc[8];
    #pragma unroll
    for (int c = 0; c < 8; ++c) acc[c] = 0.f;

    for (int e = beg + g; e < end; e += 4) {
        int sidx = esrc[e];
        u16x8 k8 = *(const u16x8*)(kb + (size_t)sidx * DD + j * 8);
        u16x8 v8 = *(const u16x8*)(vb + (size_t)sidx * DD + j * 8);
        float p;
        p  = qf[0] * bf2f(k8[0]);
        p  = fmaf(qf[1], bf2f(k8[1]), p);
        p  = fmaf(qf[2], bf2f(k8[2]), p);
        p  = fmaf(qf[3], bf2f(k8[3]), p);
        p  = fmaf(qf[4], bf2f(k8[4]), p);
        p  = fmaf(qf[5], bf2f(k8[5]), p);
        p  = fmaf(qf[6], bf2f(k8[6]), p);
        p  = fmaf(qf[7], bf2f(k8[7]), p);
        p += __shfl_xor(p, 8);
        p += __shfl_xor(p, 4);
        p += __shfl_xor(p, 2);
        p += __shfl_xor(p, 1);
        float score = p * 0.088388347648318447f;   // 1/sqrt(128)
        float mn = fmaxf(m, score);
        float scale = __expf(m - mn);
        float pe = __expf(score - mn);
        den = den * scale + pe;
        #pragma unroll
        for (int c = 0; c < 8; ++c)
            acc[c] = fmaf(acc[c], scale, pe * bf2f(v8[c]));
        m = mn;
    }

    float mo = __shfl_xor(m, 16);
    float m2 = fmaxf(m, mo);
    mo = __shfl_xor(m2, 32);
    float mf = fmaxf(m2, mo);
    float sc = __expf(m - mf);
    den *= sc;
    den += __shfl_xor(den, 16);
    den += __shfl_xor(den, 32);
    #pragma unroll
    for (int c = 0; c < 8; ++c) {
        float a = acc[c] * sc;
        a += __shfl_xor(a, 16);
        a += __shfl_xor(a, 32);
        acc[c] = a;
    }
    float inv = den > 0.f ? 1.0f / den : 0.f;
    if (g == 0) {
        u16x8 s8 = *(const u16x8*)(sb + (size_t)node * DD + j * 8);
        u16x8 o8;
        #pragma unroll
        for (int c = 0; c < 8; ++c)
            o8[c] = f2bf(fmaxf(fmaf(acc[c], inv, bf2f(s8[c])), 0.f));
        *(u16x8*)(hout + (size_t)node * DD + j * 8) = o8;
    }
}

// ---------------- global mean pool (h bf16): segmented running sum ----------

__global__ __launch_bounds__(128) void pool_kernel(const unsigned short* __restrict__ h,
                                                   const int* __restrict__ batch,
                                                   float* __restrict__ gsum,
                                                   float* __restrict__ gcnt, int n) {
    __shared__ int bsh[PCHUNK];
    int t = threadIdx.x;
    int node0 = blockIdx.x * PCHUNK;
    int nnodes = min(PCHUNK, n - node0);
    if (t < nnodes) bsh[t] = batch[node0 + t];
    __syncthreads();

    int cur = bsh[0];
    float acc = 0.f;
    int cnt = 0;
    for (int j = 0; j < nnodes; ++j) {
        int g = bsh[j];
        float val = bf2f(h[(size_t)(node0 + j) * DD + t]);
        if (g != cur) {
            atomicAdd(&gsum[cur * DD + t], acc);
            if (t == 0) atomicAdd(&gcnt[cur], (float)cnt);
            acc = 0.f; cnt = 0; cur = g;
        }
        acc += val; ++cnt;
    }
    if (cnt > 0) {
        atomicAdd(&gsum[cur * DD + t], acc);
        if (t == 0) atomicAdd(&gcnt[cur], (float)cnt);
    }
}

// ---------------- FC + log_softmax ----------------

__global__ __launch_bounds__(64) void head_kernel(
    const float* __restrict__ gsum, const float* __restrict__ gcnt,
    const float* __restrict__ wfc, const float* __restrict__ bfc,
    float* __restrict__ out) {
    int g = blockIdx.x;
    int lane = threadIdx.x;
    float cnt = fmaxf(gcnt[g], 1.0f);
    float inv = 1.0f / cnt;
    float p0 = gsum[g * DD + lane] * inv;
    float p1 = gsum[g * DD + lane + 64] * inv;
    __shared__ float logits[NCLS];
    for (int c = 0; c < NCLS; ++c) {
        float partial = p0 * wfc[lane * NCLS + c] + p1 * wfc[(lane + 64) * NCLS + c];
        partial += __shfl_xor(partial, 32);
        partial += __shfl_xor(partial, 16);
        partial += __shfl_xor(partial, 8);
        partial += __shfl_xor(partial, 4);
        partial += __shfl_xor(partial, 2);
        partial += __shfl_xor(partial, 1);
        if (lane == 0) logits[c] = partial + bfc[c];
    }
    __syncthreads();
    if (lane == 0) {
        float mx = logits[0];
        for (int c = 1; c < NCLS; ++c) mx = fmaxf(mx, logits[c]);
        float sum = 0.f;
        for (int c = 0; c < NCLS; ++c) sum += expf(logits[c] - mx);
        float lse = mx + logf(sum);
        for (int c = 0; c < NCLS; ++c) out[g * NCLS + c] = logits[c] - lse;
    }
}

// ---------------- launch ----------------

extern "C" void kernel_launch(void* const* d_in, const int* in_sizes, int n_in,
                              void* d_out, int out_size, void* d_ws, size_t ws_size,
                              hipStream_t stream) {
    const float* x     = (const float*)d_in[0];
    const int*   ei    = (const int*)d_in[1];
    const int*   batch = (const int*)d_in[2];
    const float* Wq = (const float*)d_in[3];
    const float* bq = (const float*)d_in[4];
    const float* Wk = (const float*)d_in[5];
    const float* bk = (const float*)d_in[6];
    const float* Wv = (const float*)d_in[7];
    const float* bv = (const float*)d_in[8];
    const float* Ws = (const float*)d_in[9];
    const float* bs = (const float*)d_in[10];
    const float* Wfc = (const float*)d_in[11];
    const float* bfc = (const float*)d_in[12];
    float* out = (float*)d_out;

    const size_t ND = (size_t)NN * DD;
    unsigned short* hbuf = (unsigned short*)d_ws;   // all bf16
    unsigned short* qb = hbuf + ND;
    unsigned short* sb = qb + ND;
    unsigned short* kb = sb + ND;
    unsigned short* vb = kb + ND;
    unsigned short* xb = vb + ND;                   // x converted to bf16
    unsigned short* wt = xb + ND;                   // [2][4][128][128] bf16
    int* cnt    = (int*)(wt + 2 * 4 * 16384);
    int* indptr = cnt + NN;
    int* cursor = indptr + NN + 1;
    int* esrc   = cursor + NN;
    int* lexcl  = esrc + EE;
    int* csum   = lexcl + NN;
    float* gsum = (float*)(csum + NCHUNK);
    float* gcnt = gsum + GG * DD;

    const int* src = ei;
    const int* dst = ei + EE;

    hipMemsetAsync(cnt, 0, NN * sizeof(int), stream);
    hipMemsetAsync(gsum, 0, (GG * DD + GG) * sizeof(float), stream);

    hist_kernel<<<(EE + 255) / 256, 256, 0, stream>>>(dst, cnt, EE);
    scan1_kernel<<<NCHUNK, 1024, 0, stream>>>(cnt, lexcl, csum, NN);
    scan3_kernel<<<NCHUNK, 1024, 0, stream>>>(lexcl, csum, indptr, cursor, NN, EE);
    fill_kernel<<<(EE + 255) / 256, 256, 0, stream>>>(src, dst, cursor, esrc, EE);
    wt_kernel<<<512, 256, 0, stream>>>(Wq, Wk, Wv, Ws, wt);
    x2bf_kernel<<<(int)(ND / 8 / 256), 256, 0, stream>>>(x, xb);

    for (int l = 0; l < 2; ++l) {
        size_t bo = (size_t)l * DD;
        const unsigned short* wtl = wt + (size_t)l * 4 * 16384;
        const unsigned short* xa = (l == 0) ? xb : hbuf;
        gemm_mfma<<<512, 256, 0, stream>>>(
            xa, wtl, bq + bo, bk + bo, bv + bo, bs + bo, qb, kb, vb, sb);
        attn_kernel<<<(NN + 3) / 4, 256, 0, stream>>>(
            qb, kb, vb, sb, indptr, esrc, hbuf, NN);
    }

    pool_kernel<<<(NN + PCHUNK - 1) / PCHUNK, 128, 0, stream>>>(hbuf, batch, gsum, gcnt, NN);
    head_kernel<<<GG, 64, 0, stream>>>(gsum, gcnt, Wfc, bfc, out);
}